// Round 4
// baseline (189.772 us; speedup 1.0000x reference)
//
#include <hip/hip_runtime.h>
#include <hip/hip_bf16.h>

#define BATCH 4
#define NPTS  8192
#define SPTS  2048
#define C1    128
#define C2    256
#define CIN   384   // C1+C2
#define H0    256
#define H1    128
#define NSLICE 32   // BN-stat accumulator slices (atomic contention killer)

typedef __attribute__((ext_vector_type(8))) short bf16x8;
typedef __attribute__((ext_vector_type(4))) float f32x4;

__device__ __forceinline__ unsigned short f2bf(float x) {
  union { float f; unsigned u; } v; v.f = x;
  unsigned r = v.u + 0x7fff + ((v.u >> 16) & 1);   // RNE
  return (unsigned short)(r >> 16);
}
__device__ __forceinline__ float bf2f(unsigned short u) {
  union { unsigned u; float f; } v; v.u = ((unsigned)u) << 16; return v.f;
}

// ---------------- fused prep: all input-only packing in one launch ----------------
__global__ __launch_bounds__(256) void prep_kernel(
    const float* __restrict__ p2, unsigned short* __restrict__ p2tb,
    const float* __restrict__ xyz2, float4* __restrict__ xp,
    const float* __restrict__ w0, const float* __restrict__ w1,
    unsigned short* __restrict__ Wp,
    const float* __restrict__ p1, unsigned short* __restrict__ Xp,
    float* __restrict__ stats) {
  __shared__ unsigned short shmem[64 * 136];
  int bid = blockIdx.x;
  int t = threadIdx.x;

  if (bid < 512) {  // ---- transpose p2 -> bf16 ----
    int b = bid >> 7, rem = bid & 127;
    int s0 = (rem >> 2) * 64, c0 = (rem & 3) * 64;
    const float* src = p2 + (size_t)b * C2 * SPTS;
    int ss = t & 63, cseg = t >> 6;
#pragma unroll
    for (int i = 0; i < 16; i++) {
      int cc = cseg + i * 4;
      shmem[ss * 72 + cc] = f2bf(src[(size_t)(c0 + cc) * SPTS + s0 + ss]);
    }
    __syncthreads();
    int s = t >> 2, chunk = t & 3;
    uint4 v0 = *(const uint4*)&shmem[s * 72 + chunk * 16];
    uint4 v1 = *(const uint4*)&shmem[s * 72 + chunk * 16 + 8];
    unsigned short* dst = p2tb + (size_t)b * SPTS * C2 + (size_t)(s0 + s) * C2 + c0 + chunk * 16;
    *(uint4*)dst = v0;
    *(uint4*)(dst + 8) = v1;
  } else if (bid < 1024) {  // ---- pack p1 ----
    int b2 = bid - 512;
    int b = b2 >> 7, n0 = (b2 & 127) * 64;
    int nn = t & 63, c4 = t >> 6;
#pragma unroll
    for (int i = 0; i < 32; i++) {
      int c = i * 4 + c4;
      shmem[nn * 136 + c] = f2bf(p1[((size_t)b * C1 + c) * NPTS + n0 + nn]);
    }
    __syncthreads();
    int n = t >> 2;
#pragma unroll
    for (int j = 0; j < 4; j++) {
      int ch = (t & 3) + j * 4;
      uint4 v = *(const uint4*)&shmem[n * 136 + ch * 8];
      *(uint4*)&Xp[((size_t)b * NPTS + n0 + n) * CIN + ch * 8] = v;
    }
  } else if (bid < 1056) {  // ---- prepack xyz2 ----
    int idx = (bid - 1024) * 256 + t;
    int b = idx >> 11, s = idx & (SPTS - 1);
    const float* x2 = xyz2 + (size_t)b * 3 * SPTS;
    float x = x2[s], y = x2[SPTS + s], z = x2[2 * SPTS + s];
    xp[idx] = make_float4(x, y, z, x * x + y * y + z * z);
  } else if (bid < 1184) {  // ---- pack weights ----
    int idx = ((bid - 1056) * 256 + t) * 4;
    const float* src = (idx < H0 * CIN) ? (w0 + idx) : (w1 + (idx - H0 * CIN));
    float4 v = *(const float4*)src;
    ushort4 o;
    o.x = f2bf(v.x); o.y = f2bf(v.y); o.z = f2bf(v.z); o.w = f2bf(v.w);
    *(ushort4*)(Wp + idx) = o;
  } else {  // ---- zero BN stat accumulators (NSLICE*768 floats) ----
    int i4 = ((bid - 1184) * 256 + t) * 4;
    if (i4 < NSLICE * 768) *(float4*)(stats + i4) = make_float4(0.f, 0.f, 0.f, 0.f);
  }
}

// branchless top-3 insert: distances via fmin/fmed3, indices via cndmask (EXACT)
#define INS3(d, s, e0, e1, e2, j0, j1, j2)                        \
  {                                                               \
    bool lt0 = (d) < (e0), lt1 = (d) < (e1), lt2 = (d) < (e2);    \
    j2 = lt1 ? (j1) : (lt2 ? (s) : (j2));                         \
    j1 = lt0 ? (j0) : (lt1 ? (s) : (j1));                         \
    j0 = lt0 ? (s) : (j0);                                        \
    e2 = __builtin_amdgcn_fmed3f((d), (e1), (e2));                \
    e1 = __builtin_amdgcn_fmed3f((d), (e0), (e1));                \
    e0 = fminf((d), (e0));                                        \
  }

// ---------------- 3-NN search: 16 waves/block, 128-cand chunks, 2-stage merge ----------------
__global__ __launch_bounds__(1024) void knn_kernel(
    const float* __restrict__ xyz1, const float4* __restrict__ xp,
    int* __restrict__ nidx, float* __restrict__ nw) {
  int b = blockIdx.y;
  int t = threadIdx.x;
  int lane = t & 63;
  int w = __builtin_amdgcn_readfirstlane(t >> 6);  // 0..15, wave-uniform
  int n = blockIdx.x * 64 + lane;
  const float* x1 = xyz1 + (size_t)b * 3 * NPTS;
  float px = x1[n], py = x1[NPTS + n], pz = x1[2 * NPTS + n];

  const int CHUNK = SPTS / 16;  // 128
  int sbase = w * CHUNK;
  const float4* cp = xp + (size_t)b * SPTS + sbase;

  float d0 = 3e38f, d1 = 3e38f, d2 = 3e38f;
  int i0 = 0, i1 = 0, i2 = 0;
#pragma unroll 8
  for (int j = 0; j < CHUNK; j++) {
    float4 c = cp[j];  // wave-uniform address -> scalar load
    float qc = fmaf(py, c.y, px * c.x);
    qc = fmaf(pz, c.z, qc);
    float d = fmaf(-2.f, qc, c.w);
    int s = sbase + j;
    INS3(d, s, d0, d1, d2, i0, i1, i2);
  }

  __shared__ float dsh[16][64][3];
  __shared__ int   ish[16][64][3];
  dsh[w][lane][0] = d0; dsh[w][lane][1] = d1; dsh[w][lane][2] = d2;
  ish[w][lane][0] = i0; ish[w][lane][1] = i1; ish[w][lane][2] = i2;
  __syncthreads();

  if (t < 256) {
    int g = t >> 6, q = t & 63;
    float e0 = 3e38f, e1 = 3e38f, e2 = 3e38f;
    int j0 = 0, j1 = 0, j2 = 0;
#pragma unroll
    for (int c = 0; c < 4; c++) {
#pragma unroll
      for (int k = 0; k < 3; k++) {
        float d = dsh[4 * g + c][q][k];
        int s = ish[4 * g + c][q][k];
        INS3(d, s, e0, e1, e2, j0, j1, j2);
      }
    }
    dsh[4 * g][q][0] = e0; dsh[4 * g][q][1] = e1; dsh[4 * g][q][2] = e2;
    ish[4 * g][q][0] = j0; ish[4 * g][q][1] = j1; ish[4 * g][q][2] = j2;
  }
  __syncthreads();

  if (t < 64) {
    float e0 = 3e38f, e1 = 3e38f, e2 = 3e38f;
    int j0 = 0, j1 = 0, j2 = 0;
#pragma unroll
    for (int c = 0; c < 4; c++) {
#pragma unroll
      for (int k = 0; k < 3; k++) {
        float d = dsh[4 * c][t][k];
        int s = ish[4 * c][t][k];
        INS3(d, s, e0, e1, e2, j0, j1, j2);
      }
    }
    float qq = px * px + py * py + pz * pz;
    float r0 = 1.f / (e0 + qq + 1e-8f);
    float r1 = 1.f / (e1 + qq + 1e-8f);
    float r2 = 1.f / (e2 + qq + 1e-8f);
    float rs = 1.f / (r0 + r1 + r2);
    int base = (b * NPTS + n) * 3;
    nidx[base + 0] = j0; nidx[base + 1] = j1; nidx[base + 2] = j2;
    nw[base + 0] = r0 * rs; nw[base + 1] = r1 * rs; nw[base + 2] = r2 * rs;
  }
}

// ---------------- interpolation (bf16 gather) -> Xp[b][n][128..383] bf16 ----------------
__global__ __launch_bounds__(256) void interp_kernel(
    const unsigned short* __restrict__ p2tb, const int* __restrict__ nidx,
    const float* __restrict__ nw, unsigned short* __restrict__ Xp) {
  const int PTS = 8;
  int bid = blockIdx.x;
  int b = bid / (NPTS / PTS);
  int p0 = (bid % (NPTS / PTS)) * PTS;
  int c = threadIdx.x;
  const unsigned short* base = p2tb + (size_t)b * SPTS * C2;
#pragma unroll
  for (int k = 0; k < PTS; k++) {
    int p = p0 + k;
    int ib = (b * NPTS + p) * 3;
    int i0 = nidx[ib], i1 = nidx[ib + 1], i2 = nidx[ib + 2];
    float w0v = nw[ib], w1v = nw[ib + 1], w2v = nw[ib + 2];
    float v = w0v * bf2f(base[(size_t)i0 * C2 + c]) +
              w1v * bf2f(base[(size_t)i1 * C2 + c]) +
              w2v * bf2f(base[(size_t)i2 * C2 + c]);
    Xp[((size_t)b * NPTS + p) * CIN + C1 + c] = f2bf(v);
  }
}

// ---------------- MFMA GEMM: triple-buffered, counted-vmcnt pipeline (T3+T4) ----------------
// Per K-step: waitcnt vmcnt(4) [oldest tile landed] -> s_barrier -> issue stage(t+2)
// -> ds_read tile t -> 16 MFMA. One barrier per K-step; loads never drained to 0
// except at the last tile. Safety: FIFO vmcnt ordering + symmetric per-wave issue.
template <int MT, int KD, bool OUT_BF16>
__global__ __launch_bounds__(256) void mfma_gemm_kernel(
    const unsigned short* __restrict__ A, const unsigned short* __restrict__ X,
    const float* __restrict__ bias, void* __restrict__ Yv,
    float* __restrict__ stats, int sum_off, int sq_off) {
  __shared__ unsigned short As[3][128 * 32];
  __shared__ unsigned short Bs[3][128 * 32];
  int b = blockIdx.z;
  int n0 = blockIdx.x * 128;
  int o0 = blockIdx.y * 128;
  int t = threadIdx.x;
  int lane = t & 63;
  int w = __builtin_amdgcn_readfirstlane(t >> 6);
  int mhalf = (w & 1) * 64, nhalf = (w >> 1) * 64;
  const unsigned short* Xb = X + (size_t)b * NPTS * KD;

  int rA = lane >> 2;
  int cofs = (lane & 3) * 8;

  // stage one 128x32 A-tile + B-tile pair into buffer `buf` (4 loads/thread, FIFO)
  auto stage = [&](int buf, int k0) {
#pragma unroll
    for (int q = 0; q < 2; q++) {
      int r0 = w * 32 + q * 16;
      const unsigned short* ga = A + (size_t)(o0 + r0 + rA) * KD + k0 + cofs;
      __builtin_amdgcn_global_load_lds(
          (const __attribute__((address_space(1))) void*)ga,
          (__attribute__((address_space(3))) void*)(&As[buf][r0 * 32]), 16, 0, 0);
      const unsigned short* gb = Xb + (size_t)(n0 + r0 + rA) * KD + k0 + cofs;
      __builtin_amdgcn_global_load_lds(
          (const __attribute__((address_space(1))) void*)gb,
          (__attribute__((address_space(3))) void*)(&Bs[buf][r0 * 32]), 16, 0, 0);
    }
  };

  constexpr int NT = KD / 32;
  f32x4 acc[4][4] = {};
  int mi = lane & 15, kq = (lane >> 4) * 8;

  stage(0, 0);
  stage(1, 32);

#pragma unroll
  for (int kt = 0; kt < NT; ++kt) {
    // oldest in-flight tile (kt) landed; keep the newest (kt+1) in flight
    if (kt < NT - 1) asm volatile("s_waitcnt vmcnt(4)" ::: "memory");
    else             asm volatile("s_waitcnt vmcnt(0)" ::: "memory");
    __builtin_amdgcn_s_barrier();
    asm volatile("" ::: "memory");            // pin ds_reads below the barrier
    __builtin_amdgcn_sched_barrier(0);

    if (kt + 2 < NT) stage((kt + 2) % 3, (kt + 2) * 32);

    const unsigned short* Ac = As[kt % 3];
    const unsigned short* Bc = Bs[kt % 3];
    bf16x8 af[4], bfr[4];
#pragma unroll
    for (int i = 0; i < 4; i++) {
      af[i]  = *(const bf16x8*)(Ac + (mhalf + i * 16 + mi) * 32 + kq);
      bfr[i] = *(const bf16x8*)(Bc + (nhalf + i * 16 + mi) * 32 + kq);
    }
#pragma unroll
    for (int mt = 0; mt < 4; mt++)
#pragma unroll
      for (int nt = 0; nt < 4; nt++)
        acc[mt][nt] = __builtin_amdgcn_mfma_f32_16x16x32_bf16(
            af[mt], bfr[nt], acc[mt][nt], 0, 0, 0);
    // no trailing barrier: next iteration's vmcnt+barrier provides the handoff;
    // write-after-read safe because ds_reads complete before each wave's MFMA
    // (compiler lgkmcnt), which precedes its next-iteration barrier.
  }

  int slice = ((blockIdx.x << 2) + blockIdx.z) & (NSLICE - 1);
  float* sb = stats + slice * 768 + sum_off;
  float* qb = stats + slice * 768 + sq_off;

  int rq = (lane >> 4) * 4;
#pragma unroll
  for (int mt = 0; mt < 4; mt++) {
#pragma unroll
    for (int r = 0; r < 4; r++) {
      int m = o0 + mhalf + mt * 16 + rq + r;
      float bv = bias[m];
      float ps = 0.f, pq = 0.f;
#pragma unroll
      for (int nt = 0; nt < 4; nt++) {
        int n = n0 + nhalf + nt * 16 + mi;
        float v = acc[mt][nt][r] + bv;
        ps += v; pq += v * v;
        if constexpr (OUT_BF16) {
          unsigned short* Y = (unsigned short*)Yv + (size_t)b * MT * NPTS;
          Y[(size_t)m * NPTS + n] = f2bf(v);
        } else {
          float* Y = (float*)Yv + (size_t)b * MT * NPTS;
          Y[(size_t)m * NPTS + n] = v;
        }
      }
      // 16 lanes of a rq-group share channel m -> butterfly reduce, 1 atomic pair
#pragma unroll
      for (int off = 1; off < 16; off <<= 1) {
        ps += __shfl_xor(ps, off, 16);
        pq += __shfl_xor(pq, off, 16);
      }
      if (mi == 0) {
        atomicAdd(&sb[m], ps);
        atomicAdd(&qb[m], pq);
      }
    }
  }
}

// ---------------- BN0 apply + ReLU + transpose (stats from 32 slices) ----------------
__global__ __launch_bounds__(256) void bn0_apply_kernel(
    const unsigned short* __restrict__ Y0, const float* __restrict__ stats,
    const float* __restrict__ gamma, const float* __restrict__ beta,
    unsigned short* __restrict__ X1) {
  __shared__ unsigned short tile[64][80];
  __shared__ float aS[64], sS[64];
  int b = blockIdx.z, o0 = blockIdx.y * 64, n0 = blockIdx.x * 64;
  int t = threadIdx.x;
  if (t < 64) {
    float ms = 0.f, vs = 0.f;
#pragma unroll
    for (int sl = 0; sl < NSLICE; sl++) {
      ms += stats[sl * 768 + o0 + t];
      vs += stats[sl * 768 + 256 + o0 + t];
    }
    const float inv = 1.f / (float)(BATCH * NPTS);
    float mean = ms * inv;
    float var = vs * inv - mean * mean;
    float ia = gamma[o0 + t] * rsqrtf(var + 1e-5f);
    aS[t] = ia; sS[t] = beta[o0 + t] - mean * ia;
  }
  __syncthreads();
  int nn = t & 63, o4 = t >> 6;
#pragma unroll
  for (int i = 0; i < 16; i++) {
    int o = i * 4 + o4;
    float v = bf2f(Y0[((size_t)b * H0 + o0 + o) * NPTS + n0 + nn]);
    v = fmaxf(v * aS[o] + sS[o], 0.f);
    tile[nn][o] = f2bf(v);
  }
  __syncthreads();
  int n = t >> 2;
#pragma unroll
  for (int j = 0; j < 2; j++) {
    int ch = (t & 3) + j * 4;
    uint4 v = *(const uint4*)&tile[n][ch * 8];
    *(uint4*)&X1[((size_t)b * NPTS + n0 + n) * H0 + o0 + ch * 8] = v;
  }
}

// ---------------- final BN+ReLU in-place on d_out (stats from 32 slices) ----------------
__global__ __launch_bounds__(256) void bn_apply_kernel(
    float* __restrict__ Y, const float* __restrict__ stats,
    const float* __restrict__ gamma, const float* __restrict__ beta) {
  __shared__ float sh2[2];
  int idx0 = blockIdx.x * 1024;          // 1024 contiguous fp32 per block
  int c = (idx0 >> 13) & (H1 - 1);       // single channel per block (1024 | 8192)
  int t = threadIdx.x;
  if (t < 32) {
    float ms = stats[t * 768 + 512 + c];
    float vs = stats[t * 768 + 640 + c];
#pragma unroll
    for (int off = 16; off > 0; off >>= 1) {
      ms += __shfl_down(ms, off, 32);
      vs += __shfl_down(vs, off, 32);
    }
    if (t == 0) {
      const float inv = 1.f / (float)(BATCH * NPTS);
      float mean = ms * inv;
      float var = vs * inv - mean * mean;
      float ia = gamma[c] * rsqrtf(var + 1e-5f);
      sh2[0] = ia; sh2[1] = beta[c] - mean * ia;
    }
  }
  __syncthreads();
  float ia = sh2[0], sh = sh2[1];
  int i = idx0 + t * 4;
  float4 v = *(float4*)(Y + i);
  v.x = fmaxf(v.x * ia + sh, 0.f);
  v.y = fmaxf(v.y * ia + sh, 0.f);
  v.z = fmaxf(v.z * ia + sh, 0.f);
  v.w = fmaxf(v.w * ia + sh, 0.f);
  *(float4*)(Y + i) = v;
}

extern "C" void kernel_launch(void* const* d_in, const int* in_sizes, int n_in,
                              void* d_out, int out_size, void* d_ws, size_t ws_size,
                              hipStream_t stream) {
  const float* xyz1    = (const float*)d_in[0];
  const float* xyz2    = (const float*)d_in[1];
  const float* points1 = (const float*)d_in[2];
  const float* points2 = (const float*)d_in[3];
  const float* w0      = (const float*)d_in[4];
  const float* b0      = (const float*)d_in[5];
  const float* gamma0  = (const float*)d_in[6];
  const float* beta0   = (const float*)d_in[7];
  const float* w1      = (const float*)d_in[8];
  const float* b1      = (const float*)d_in[9];
  const float* gamma1  = (const float*)d_in[10];
  const float* beta1   = (const float*)d_in[11];
  float* out = (float*)d_out;

  char* ws = (char*)d_ws;
  unsigned short* p2tb = (unsigned short*)ws;  ws += (size_t)BATCH * SPTS * C2 * 2;   // 4.2 MB
  unsigned short* Xp = (unsigned short*)ws;    ws += (size_t)BATCH * NPTS * CIN * 2;  // 25.2 MB
  unsigned short* Y0 = (unsigned short*)ws;    ws += (size_t)BATCH * H0 * NPTS * 2;   // 16.8 MB
  unsigned short* X1 = (unsigned short*)ws;    ws += (size_t)BATCH * NPTS * H0 * 2;   // 16.8 MB
  unsigned short* Wp = (unsigned short*)ws;    ws += (size_t)(H0 * CIN + H1 * H0) * 2;
  int* nidx = (int*)ws;                        ws += (size_t)BATCH * NPTS * 3 * 4;
  float* nw = (float*)ws;                      ws += (size_t)BATCH * NPTS * 3 * 4;
  float4* xyz2p = (float4*)(((uintptr_t)ws + 15) & ~(uintptr_t)15);
  ws = (char*)xyz2p + (size_t)BATCH * SPTS * 16;
  float* stats = (float*)ws;                   ws += (size_t)NSLICE * 768 * 4;  // 96 KB
  // per-slice layout: [0,256)=sum0, [256,512)=sq0, [512,640)=sum1, [640,768)=sq1
  (void)ws_size; (void)in_sizes; (void)n_in; (void)out_size;

  prep_kernel<<<dim3(1208), 256, 0, stream>>>(points2, p2tb, xyz2, xyz2p,
                                              w0, w1, Wp, points1, Xp, stats);
  knn_kernel<<<dim3(NPTS / 64, BATCH), 1024, 0, stream>>>(xyz1, xyz2p, nidx, nw);
  interp_kernel<<<dim3(BATCH * NPTS / 8), 256, 0, stream>>>(p2tb, nidx, nw, Xp);

  mfma_gemm_kernel<H0, CIN, true><<<dim3(NPTS / 128, H0 / 128, BATCH), 256, 0, stream>>>(
      Wp, Xp, b0, Y0, stats, 0, 256);
  bn0_apply_kernel<<<dim3(NPTS / 64, H0 / 64, BATCH), 256, 0, stream>>>(
      Y0, stats, gamma0, beta0, X1);
  mfma_gemm_kernel<H1, H0, false><<<dim3(NPTS / 128, H1 / 128, BATCH), 256, 0, stream>>>(
      Wp + H0 * CIN, X1, b1, out, stats, 512, 640);
  bn_apply_kernel<<<dim3(BATCH * H1 * NPTS / 1024), 256, 0, stream>>>(
      out, stats, gamma1, beta1);
}

// Round 5
// 180.800 us; speedup vs baseline: 1.0496x; 1.0496x over previous
//
#include <hip/hip_runtime.h>
#include <hip/hip_bf16.h>

#define BATCH 4
#define NPTS  8192
#define SPTS  2048
#define C1    128
#define C2    256
#define CIN   384   // C1+C2
#define H0    256
#define H1    128
#define NSLICE 32   // BN-stat accumulator slices

typedef __attribute__((ext_vector_type(8))) short bf16x8;
typedef __attribute__((ext_vector_type(4))) float f32x4;

__device__ __forceinline__ unsigned short f2bf(float x) {
  union { float f; unsigned u; } v; v.f = x;
  unsigned r = v.u + 0x7fff + ((v.u >> 16) & 1);   // RNE
  return (unsigned short)(r >> 16);
}
__device__ __forceinline__ float bf2f(unsigned short u) {
  union { unsigned u; float f; } v; v.u = ((unsigned)u) << 16; return v.f;
}

// ---------------- fused prep: all input-only packing in one launch ----------------
// seg A [0,512):    transpose points2 (B,C2,S) fp32 -> p2tb (B,S,C2) bf16
// seg B [512,1024): pack points1 (B,C1,N) fp32 -> Xp[b][n][0..127] bf16
// seg C [1024,1056): prepack xyz2 (B,3,S) -> float4 (-2x,-2y,-2z,|c|^2)
// seg D [1056,1184): weights fp32 -> bf16 (Wp0 256x384, then Wp1 128x256)
// seg E [1184,1208): zero BN stat accumulators
__global__ __launch_bounds__(256) void prep_kernel(
    const float* __restrict__ p2, unsigned short* __restrict__ p2tb,
    const float* __restrict__ xyz2, float4* __restrict__ xp,
    const float* __restrict__ w0, const float* __restrict__ w1,
    unsigned short* __restrict__ Wp,
    const float* __restrict__ p1, unsigned short* __restrict__ Xp,
    float* __restrict__ stats) {
  __shared__ unsigned short shmem[64 * 136];
  int bid = blockIdx.x;
  int t = threadIdx.x;

  if (bid < 512) {  // ---- transpose p2 -> bf16 ----
    int b = bid >> 7, rem = bid & 127;
    int s0 = (rem >> 2) * 64, c0 = (rem & 3) * 64;
    const float* src = p2 + (size_t)b * C2 * SPTS;
    int ss = t & 63, cseg = t >> 6;
#pragma unroll
    for (int i = 0; i < 16; i++) {
      int cc = cseg + i * 4;
      shmem[ss * 72 + cc] = f2bf(src[(size_t)(c0 + cc) * SPTS + s0 + ss]);
    }
    __syncthreads();
    int s = t >> 2, chunk = t & 3;
    uint4 v0 = *(const uint4*)&shmem[s * 72 + chunk * 16];
    uint4 v1 = *(const uint4*)&shmem[s * 72 + chunk * 16 + 8];
    unsigned short* dst = p2tb + (size_t)b * SPTS * C2 + (size_t)(s0 + s) * C2 + c0 + chunk * 16;
    *(uint4*)dst = v0;
    *(uint4*)(dst + 8) = v1;
  } else if (bid < 1024) {  // ---- pack p1 ----
    int b2 = bid - 512;
    int b = b2 >> 7, n0 = (b2 & 127) * 64;
    int nn = t & 63, c4 = t >> 6;
#pragma unroll
    for (int i = 0; i < 32; i++) {
      int c = i * 4 + c4;
      shmem[nn * 136 + c] = f2bf(p1[((size_t)b * C1 + c) * NPTS + n0 + nn]);
    }
    __syncthreads();
    int n = t >> 2;
#pragma unroll
    for (int j = 0; j < 4; j++) {
      int ch = (t & 3) + j * 4;
      uint4 v = *(const uint4*)&shmem[n * 136 + ch * 8];
      *(uint4*)&Xp[((size_t)b * NPTS + n0 + n) * CIN + ch * 8] = v;
    }
  } else if (bid < 1056) {  // ---- prepack xyz2 (pre-negated, doubled) ----
    int idx = (bid - 1024) * 256 + t;
    int b = idx >> 11, s = idx & (SPTS - 1);
    const float* x2 = xyz2 + (size_t)b * 3 * SPTS;
    float x = x2[s], y = x2[SPTS + s], z = x2[2 * SPTS + s];
    xp[idx] = make_float4(-2.f * x, -2.f * y, -2.f * z, x * x + y * y + z * z);
  } else if (bid < 1184) {  // ---- pack weights ----
    int idx = ((bid - 1056) * 256 + t) * 4;
    const float* src = (idx < H0 * CIN) ? (w0 + idx) : (w1 + (idx - H0 * CIN));
    float4 v = *(const float4*)src;
    ushort4 o;
    o.x = f2bf(v.x); o.y = f2bf(v.y); o.z = f2bf(v.z); o.w = f2bf(v.w);
    *(ushort4*)(Wp + idx) = o;
  } else {  // ---- zero BN stat accumulators ----
    int i4 = ((bid - 1184) * 256 + t) * 4;
    if (i4 < NSLICE * 768) *(float4*)(stats + i4) = make_float4(0.f, 0.f, 0.f, 0.f);
  }
}

// branchless top-3 insert: distances via fmin/fmed3, indices via cndmask (EXACT)
#define INS3(d, s, e0, e1, e2, j0, j1, j2)                        \
  {                                                               \
    bool lt0 = (d) < (e0), lt1 = (d) < (e1), lt2 = (d) < (e2);    \
    j2 = lt1 ? (j1) : (lt2 ? (s) : (j2));                         \
    j1 = lt0 ? (j0) : (lt1 ? (s) : (j1));                         \
    j0 = lt0 ? (s) : (j0);                                        \
    e2 = __builtin_amdgcn_fmed3f((d), (e1), (e2));                \
    e1 = __builtin_amdgcn_fmed3f((d), (e0), (e1));                \
    e0 = fminf((d), (e0));                                        \
  }

// ---------------- 3-NN search + fused interpolation ----------------
// 16 waves search 128-cand chunks; 2-stage merge; idx/weights kept in LDS;
// then all 1024 threads gather-blend p2tb into Xp[b][n][128..383].
__global__ __launch_bounds__(1024) void knn_interp_kernel(
    const float* __restrict__ xyz1, const float4* __restrict__ xp,
    const unsigned short* __restrict__ p2tb, unsigned short* __restrict__ Xp) {
  int b = blockIdx.y;
  int t = threadIdx.x;
  int lane = t & 63;
  int w = __builtin_amdgcn_readfirstlane(t >> 6);  // 0..15
  int n = blockIdx.x * 64 + lane;
  const float* x1 = xyz1 + (size_t)b * 3 * NPTS;
  float px = x1[n], py = x1[NPTS + n], pz = x1[2 * NPTS + n];

  const int CHUNK = SPTS / 16;  // 128
  int sbase = w * CHUNK;
  const float4* cp = xp + (size_t)b * SPTS + sbase;

  float d0 = 3e38f, d1 = 3e38f, d2 = 3e38f;
  int i0 = 0, i1 = 0, i2 = 0;
#pragma unroll 8
  for (int j = 0; j < CHUNK; j++) {
    float4 c = cp[j];  // wave-uniform address -> scalar load
    // d' = |c|^2 - 2 q.c  (3 fma; c pre-negated/doubled)
    float d = fmaf(c.z, pz, fmaf(c.y, py, fmaf(c.x, px, c.w)));
    int s = sbase + j;
    INS3(d, s, d0, d1, d2, i0, i1, i2);
  }

  __shared__ float dsh[16][64][3];
  __shared__ int   ish[16][64][3];
  __shared__ int   widx[64][3];
  __shared__ float wwgt[64][3];
  dsh[w][lane][0] = d0; dsh[w][lane][1] = d1; dsh[w][lane][2] = d2;
  ish[w][lane][0] = i0; ish[w][lane][1] = i1; ish[w][lane][2] = i2;
  __syncthreads();

  if (t < 256) {  // stage B: 4 groups merge 4 lists each
    int g = t >> 6, q = t & 63;
    float e0 = 3e38f, e1 = 3e38f, e2 = 3e38f;
    int j0 = 0, j1 = 0, j2 = 0;
#pragma unroll
    for (int c = 0; c < 4; c++) {
#pragma unroll
      for (int k = 0; k < 3; k++) {
        float d = dsh[4 * g + c][q][k];
        int s = ish[4 * g + c][q][k];
        INS3(d, s, e0, e1, e2, j0, j1, j2);
      }
    }
    dsh[4 * g][q][0] = e0; dsh[4 * g][q][1] = e1; dsh[4 * g][q][2] = e2;
    ish[4 * g][q][0] = j0; ish[4 * g][q][1] = j1; ish[4 * g][q][2] = j2;
  }
  __syncthreads();

  if (t < 64) {  // stage C: final merge; weights -> LDS
    float e0 = 3e38f, e1 = 3e38f, e2 = 3e38f;
    int j0 = 0, j1 = 0, j2 = 0;
#pragma unroll
    for (int c = 0; c < 4; c++) {
#pragma unroll
      for (int k = 0; k < 3; k++) {
        float d = dsh[4 * c][t][k];
        int s = ish[4 * c][t][k];
        INS3(d, s, e0, e1, e2, j0, j1, j2);
      }
    }
    float qq = fmaf(px, px, fmaf(py, py, pz * pz));
    float r0 = 1.f / (e0 + qq + 1e-8f);
    float r1 = 1.f / (e1 + qq + 1e-8f);
    float r2 = 1.f / (e2 + qq + 1e-8f);
    float rs = 1.f / (r0 + r1 + r2);
    widx[t][0] = j0; widx[t][1] = j1; widx[t][2] = j2;
    wwgt[t][0] = r0 * rs; wwgt[t][1] = r1 * rs; wwgt[t][2] = r2 * rs;
  }
  __syncthreads();

  // ---- fused interpolation: 64 points x 256 channels, 2 channels/thread/iter ----
  const unsigned short* base = p2tb + (size_t)b * SPTS * C2;
  int c2 = (t & 127) * 2;    // channel pair
  int psub = t >> 7;         // 0..7
  unsigned short* xrow = Xp + ((size_t)b * NPTS + blockIdx.x * 64) * CIN + C1 + c2;
#pragma unroll
  for (int i = 0; i < 8; i++) {
    int pl = psub + i * 8;
    int g0 = widx[pl][0], g1 = widx[pl][1], g2 = widx[pl][2];
    float w0v = wwgt[pl][0], w1v = wwgt[pl][1], w2v = wwgt[pl][2];
    unsigned a0 = *(const unsigned*)(base + (size_t)g0 * C2 + c2);
    unsigned a1 = *(const unsigned*)(base + (size_t)g1 * C2 + c2);
    unsigned a2 = *(const unsigned*)(base + (size_t)g2 * C2 + c2);
    float v0 = w0v * bf2f((unsigned short)a0) + w1v * bf2f((unsigned short)a1) +
               w2v * bf2f((unsigned short)a2);
    float v1 = w0v * bf2f((unsigned short)(a0 >> 16)) + w1v * bf2f((unsigned short)(a1 >> 16)) +
               w2v * bf2f((unsigned short)(a2 >> 16));
    unsigned pk = (unsigned)f2bf(v0) | ((unsigned)f2bf(v1) << 16);
    *(unsigned*)(xrow + (size_t)pl * CIN) = pk;
  }
}

// ---------------- GEMM0: Wp0(256x384) x Xp^T -> Y0 [b][n][256] bf16 (transposed epilogue)
// triple-buffered counted-vmcnt K-loop; fused BN0 stats (sliced atomics).
__global__ __launch_bounds__(256) void gemm0_kernel(
    const unsigned short* __restrict__ A, const unsigned short* __restrict__ X,
    const float* __restrict__ bias, unsigned short* __restrict__ Y0,
    float* __restrict__ stats) {
  constexpr int KD = CIN;  // 384
  __shared__ unsigned short lds[24576];  // 48KB: As[3]@0, Bs[3]@12288; epilogue tile[128][136]
  int b = blockIdx.z;
  int n0 = blockIdx.x * 128;
  int o0 = blockIdx.y * 128;
  int t = threadIdx.x;
  int lane = t & 63;
  int w = __builtin_amdgcn_readfirstlane(t >> 6);
  int mhalf = (w & 1) * 64, nhalf = (w >> 1) * 64;
  const unsigned short* Xb = X + (size_t)b * NPTS * KD;
  int rA = lane >> 2;
  int cofs = (lane & 3) * 8;

  auto stage = [&](int buf, int k0) {
#pragma unroll
    for (int q = 0; q < 2; q++) {
      int r0 = w * 32 + q * 16;
      const unsigned short* ga = A + (size_t)(o0 + r0 + rA) * KD + k0 + cofs;
      __builtin_amdgcn_global_load_lds(
          (const __attribute__((address_space(1))) void*)ga,
          (__attribute__((address_space(3))) void*)(lds + buf * 4096 + r0 * 32), 16, 0, 0);
      const unsigned short* gb = Xb + (size_t)(n0 + r0 + rA) * KD + k0 + cofs;
      __builtin_amdgcn_global_load_lds(
          (const __attribute__((address_space(1))) void*)gb,
          (__attribute__((address_space(3))) void*)(lds + 12288 + buf * 4096 + r0 * 32), 16, 0, 0);
    }
  };

  constexpr int NT = KD / 32;  // 12
  f32x4 acc[4][4] = {};
  int mi = lane & 15, kq = (lane >> 4) * 8;

  stage(0, 0);
  stage(1, 32);

#pragma unroll
  for (int kt = 0; kt < NT; ++kt) {
    if (kt < NT - 1) asm volatile("s_waitcnt vmcnt(4)" ::: "memory");
    else             asm volatile("s_waitcnt vmcnt(0)" ::: "memory");
    __builtin_amdgcn_s_barrier();
    asm volatile("" ::: "memory");
    __builtin_amdgcn_sched_barrier(0);

    if (kt + 2 < NT) stage((kt + 2) % 3, (kt + 2) * 32);

    const unsigned short* Ac = lds + (kt % 3) * 4096;
    const unsigned short* Bc = lds + 12288 + (kt % 3) * 4096;
    bf16x8 af[4], bfr[4];
#pragma unroll
    for (int i = 0; i < 4; i++) {
      af[i]  = *(const bf16x8*)(Ac + (mhalf + i * 16 + mi) * 32 + kq);
      bfr[i] = *(const bf16x8*)(Bc + (nhalf + i * 16 + mi) * 32 + kq);
    }
#pragma unroll
    for (int mt = 0; mt < 4; mt++)
#pragma unroll
      for (int nt = 0; nt < 4; nt++)
        acc[mt][nt] = __builtin_amdgcn_mfma_f32_16x16x32_bf16(
            af[mt], bfr[nt], acc[mt][nt], 0, 0, 0);
  }

  __syncthreads();  // all MFMA consumed LDS; safe to reuse as transpose tile

  int slice = ((blockIdx.x << 2) + blockIdx.z) & (NSLICE - 1);
  float* sb = stats + slice * 768;        // sum0
  float* qb = stats + slice * 768 + 256;  // sq0

  int rq = (lane >> 4) * 4;
#pragma unroll
  for (int mt = 0; mt < 4; mt++) {
#pragma unroll
    for (int r = 0; r < 4; r++) {
      int ml = mhalf + mt * 16 + rq + r;
      float bv = bias[o0 + ml];
      float ps = 0.f, pq = 0.f;
#pragma unroll
      for (int nt = 0; nt < 4; nt++) {
        int nl = nhalf + nt * 16 + mi;
        float v = acc[mt][nt][r] + bv;
        ps += v; pq += v * v;
        lds[nl * 136 + ml] = f2bf(v);   // [n_local][m_local] transpose tile
      }
#pragma unroll
      for (int off = 1; off < 16; off <<= 1) {
        ps += __shfl_xor(ps, off, 16);
        pq += __shfl_xor(pq, off, 16);
      }
      if (mi == 0) {
        atomicAdd(&sb[o0 + ml], ps);
        atomicAdd(&qb[o0 + ml], pq);
      }
    }
  }
  __syncthreads();

  // coalesced store: Y0[b][n0+row][o0 .. o0+127]
  int row = t >> 1, ch0 = (t & 1) * 64;
  unsigned short* Yr = Y0 + ((size_t)b * NPTS + n0 + row) * H0 + o0 + ch0;
#pragma unroll
  for (int j = 0; j < 8; j++) {
    uint4 v = *(const uint4*)&lds[row * 136 + ch0 + j * 8];
    *(uint4*)(Yr + j * 8) = v;
  }
}

// ---------------- GEMM1: Wp1(128x256) x (BN0+ReLU applied on-the-fly to Y0[n][256])
// B reg-staged with fused BN0; double-buffered, 1 barrier per K-step; fused BN1 stats.
__global__ __launch_bounds__(256) void gemm1_kernel(
    const unsigned short* __restrict__ A, const unsigned short* __restrict__ Y0,
    const float* __restrict__ bias, float* __restrict__ out,
    float* __restrict__ stats, const float* __restrict__ gamma0,
    const float* __restrict__ beta0) {
  constexpr int KD = H0;  // 256
  __shared__ unsigned short As[2][4096];
  __shared__ unsigned short Bs[2][4096];
  __shared__ float aS[256], sS[256];
  int b = blockIdx.z;
  int n0 = blockIdx.x * 128;
  int t = threadIdx.x;
  int lane = t & 63;
  int w = __builtin_amdgcn_readfirstlane(t >> 6);
  int mhalf = (w & 1) * 64, nhalf = (w >> 1) * 64;
  int rA = lane >> 2;
  int cofs = (lane & 3) * 8;
  const unsigned short* Yb = Y0 + ((size_t)b * NPTS + n0) * KD;

  // BN0 coefficients from 32-slice stats (channel = t)
  {
    float ms = 0.f, vs = 0.f;
#pragma unroll 8
    for (int sl = 0; sl < NSLICE; sl++) {
      ms += stats[sl * 768 + t];
      vs += stats[sl * 768 + 256 + t];
    }
    const float inv = 1.f / (float)(BATCH * NPTS);
    float mean = ms * inv;
    float var = vs * inv - mean * mean;
    float ia = gamma0[t] * rsqrtf(var + 1e-5f);
    aS[t] = ia; sS[t] = beta0[t] - mean * ia;
  }
  __syncthreads();

  auto stageA = [&](int buf, int k0) {
#pragma unroll
    for (int q = 0; q < 2; q++) {
      int r0 = w * 32 + q * 16;
      const unsigned short* ga = A + (size_t)(r0 + rA) * KD + k0 + cofs;
      __builtin_amdgcn_global_load_lds(
          (const __attribute__((address_space(1))) void*)ga,
          (__attribute__((address_space(3))) void*)(&As[buf][r0 * 32]), 16, 0, 0);
    }
  };
  bf16x8 br[2];
  auto loadB = [&](int k0) {
#pragma unroll
    for (int q = 0; q < 2; q++) {
      int r0 = w * 32 + q * 16;
      br[q] = *(const bf16x8*)(Yb + (size_t)(r0 + rA) * KD + k0 + cofs);
    }
  };
  auto writeB = [&](int buf, int k0) {
#pragma unroll
    for (int q = 0; q < 2; q++) {
      int r0 = w * 32 + q * 16;
      bf16x8 v = br[q], o;
#pragma unroll
      for (int e = 0; e < 8; e++) {
        float f = bf2f((unsigned short)v[e]);
        f = fmaxf(fmaf(f, aS[k0 + cofs + e], sS[k0 + cofs + e]), 0.f);
        o[e] = (short)f2bf(f);
      }
      *(bf16x8*)(&Bs[buf][(r0 + rA) * 32 + cofs]) = o;
    }
  };

  constexpr int NT = KD / 32;  // 8
  f32x4 acc[4][4] = {};
  int mi = lane & 15, kq = (lane >> 4) * 8;

  stageA(0, 0);
  loadB(0);
  int buf = 0;
#pragma unroll
  for (int kt = 0; kt < NT; ++kt) {
    asm volatile("s_waitcnt vmcnt(0)" ::: "memory");   // A(kt) in LDS, B(kt) in regs
    __builtin_amdgcn_sched_barrier(0);
    writeB(buf, kt * 32);                              // BN0+ReLU transform -> LDS
    asm volatile("s_waitcnt lgkmcnt(0)" ::: "memory");
    asm volatile("s_barrier" ::: "memory");
    __builtin_amdgcn_sched_barrier(0);
    if (kt + 1 < NT) { stageA(buf ^ 1, (kt + 1) * 32); loadB((kt + 1) * 32); }

    bf16x8 af[4], bfr[4];
#pragma unroll
    for (int i = 0; i < 4; i++) {
      af[i]  = *(const bf16x8*)(&As[buf][(mhalf + i * 16 + mi) * 32 + kq]);
      bfr[i] = *(const bf16x8*)(&Bs[buf][(nhalf + i * 16 + mi) * 32 + kq]);
    }
#pragma unroll
    for (int mt = 0; mt < 4; mt++)
#pragma unroll
      for (int nt = 0; nt < 4; nt++)
        acc[mt][nt] = __builtin_amdgcn_mfma_f32_16x16x32_bf16(
            af[mt], bfr[nt], acc[mt][nt], 0, 0, 0);
    buf ^= 1;
  }

  int slice = ((blockIdx.x << 2) + blockIdx.z) & (NSLICE - 1);
  float* sb = stats + slice * 768 + 512;  // sum1
  float* qb = stats + slice * 768 + 640;  // sq1
  float* Yo = out + (size_t)b * H1 * NPTS;

  int rq = (lane >> 4) * 4;
#pragma unroll
  for (int mt = 0; mt < 4; mt++) {
#pragma unroll
    for (int r = 0; r < 4; r++) {
      int m = mhalf + mt * 16 + rq + r;
      float bv = bias[m];
      float ps = 0.f, pq = 0.f;
#pragma unroll
      for (int nt = 0; nt < 4; nt++) {
        int n = n0 + nhalf + nt * 16 + mi;
        float v = acc[mt][nt][r] + bv;
        ps += v; pq += v * v;
        Yo[(size_t)m * NPTS + n] = v;
      }
#pragma unroll
      for (int off = 1; off < 16; off <<= 1) {
        ps += __shfl_xor(ps, off, 16);
        pq += __shfl_xor(pq, off, 16);
      }
      if (mi == 0) {
        atomicAdd(&sb[m], ps);
        atomicAdd(&qb[m], pq);
      }
    }
  }
}

// ---------------- final BN+ReLU in-place on d_out (stats from 32 slices) ----------------
__global__ __launch_bounds__(256) void bn_apply_kernel(
    float* __restrict__ Y, const float* __restrict__ stats,
    const float* __restrict__ gamma, const float* __restrict__ beta) {
  __shared__ float sh2[2];
  int idx0 = blockIdx.x * 1024;          // 1024 contiguous fp32 per block
  int c = (idx0 >> 13) & (H1 - 1);       // single channel per block (1024 | 8192)
  int t = threadIdx.x;
  if (t < 32) {
    float ms = stats[t * 768 + 512 + c];
    float vs = stats[t * 768 + 640 + c];
#pragma unroll
    for (int off = 16; off > 0; off >>= 1) {
      ms += __shfl_down(ms, off, 32);
      vs += __shfl_down(vs, off, 32);
    }
    if (t == 0) {
      const float inv = 1.f / (float)(BATCH * NPTS);
      float mean = ms * inv;
      float var = vs * inv - mean * mean;
      float ia = gamma[c] * rsqrtf(var + 1e-5f);
      sh2[0] = ia; sh2[1] = beta[c] - mean * ia;
    }
  }
  __syncthreads();
  float ia = sh2[0], sh = sh2[1];
  int i = idx0 + t * 4;
  float4 v = *(float4*)(Y + i);
  v.x = fmaxf(v.x * ia + sh, 0.f);
  v.y = fmaxf(v.y * ia + sh, 0.f);
  v.z = fmaxf(v.z * ia + sh, 0.f);
  v.w = fmaxf(v.w * ia + sh, 0.f);
  *(float4*)(Y + i) = v;
}

extern "C" void kernel_launch(void* const* d_in, const int* in_sizes, int n_in,
                              void* d_out, int out_size, void* d_ws, size_t ws_size,
                              hipStream_t stream) {
  const float* xyz1    = (const float*)d_in[0];
  const float* xyz2    = (const float*)d_in[1];
  const float* points1 = (const float*)d_in[2];
  const float* points2 = (const float*)d_in[3];
  const float* w0      = (const float*)d_in[4];
  const float* b0      = (const float*)d_in[5];
  const float* gamma0  = (const float*)d_in[6];
  const float* beta0   = (const float*)d_in[7];
  const float* w1      = (const float*)d_in[8];
  const float* b1      = (const float*)d_in[9];
  const float* gamma1  = (const float*)d_in[10];
  const float* beta1   = (const float*)d_in[11];
  float* out = (float*)d_out;

  char* ws = (char*)d_ws;
  unsigned short* p2tb = (unsigned short*)ws;  ws += (size_t)BATCH * SPTS * C2 * 2;   // 4.2 MB
  unsigned short* Xp = (unsigned short*)ws;    ws += (size_t)BATCH * NPTS * CIN * 2;  // 25.2 MB
  unsigned short* Y0 = (unsigned short*)ws;    ws += (size_t)BATCH * NPTS * H0 * 2;   // 16.8 MB ([b][n][o])
  unsigned short* Wp = (unsigned short*)ws;    ws += (size_t)(H0 * CIN + H1 * H0) * 2;
  float4* xyz2p = (float4*)(((uintptr_t)ws + 15) & ~(uintptr_t)15);
  ws = (char*)xyz2p + (size_t)BATCH * SPTS * 16;
  float* stats = (float*)ws;                   ws += (size_t)NSLICE * 768 * 4;  // 96 KB
  // per-slice layout: [0,256)=sum0, [256,512)=sq0, [512,640)=sum1, [640,768)=sq1
  (void)ws_size; (void)in_sizes; (void)n_in; (void)out_size;

  prep_kernel<<<dim3(1208), 256, 0, stream>>>(points2, p2tb, xyz2, xyz2p,
                                              w0, w1, Wp, points1, Xp, stats);
  knn_interp_kernel<<<dim3(NPTS / 64, BATCH), 1024, 0, stream>>>(xyz1, xyz2p, p2tb, Xp);
  gemm0_kernel<<<dim3(NPTS / 128, H0 / 128, BATCH), 256, 0, stream>>>(
      Wp, Xp, b0, Y0, stats);
  gemm1_kernel<<<dim3(NPTS / 128, 1, BATCH), 256, 0, stream>>>(
      Wp + H0 * CIN, Y0, b1, out, stats, gamma0, beta0);
  bn_apply_kernel<<<dim3(BATCH * H1 * NPTS / 1024), 256, 0, stream>>>(
      out, stats, gamma1, beta1);
}